// Round 1
// baseline (190.829 us; speedup 1.0000x reference)
//
#include <hip/hip_runtime.h>

#define D 256           // embedding dim
#define D4 (D/4)        // float4 chunks per row == 64 == wave size

__device__ inline float dot4(const float4 u, const float4 v) {
    return u.x*v.x + u.y*v.y + u.z*v.z + u.w*v.w;
}

// full 64-lane butterfly sum
__device__ inline float wsum(float v) {
    #pragma unroll
    for (int off = 32; off > 0; off >>= 1)
        v += __shfl_xor(v, off, 64);
    return v;
}

__global__ __launch_bounds__(256) void transint_kernel(
    const int*   __restrict__ pos_h,
    const int*   __restrict__ pos_t,
    const int*   __restrict__ pos_r,
    const int*   __restrict__ neg_h,
    const int*   __restrict__ neg_t,
    const float* __restrict__ ent_emb,   // [E, D]
    const float* __restrict__ heads,     // [K, D]
    const float* __restrict__ bases,     // [R, 2, D]
    const int*   __restrict__ rel2head,  // [R]
    const float* __restrict__ rel2mult,  // [R]
    float*       __restrict__ out,       // [2*B]  (pos scores, then neg scores)
    int nB)
{
    const int wave = (blockIdx.x * blockDim.x + threadIdx.x) >> 6;
    const int lane = threadIdx.x & 63;
    if (wave >= nB) return;
    const int b = wave;

    const int r  = pos_r[b];
    const int ph = pos_h[b];
    const int pt = pos_t[b];
    const int nh = neg_h[b];
    const int nt = neg_t[b];
    const int hd = rel2head[r];
    const float mult = rel2mult[r];

    const float4* e    = (const float4*)ent_emb;                          // row stride D4
    const float4* hrow = (const float4*)(heads + (size_t)hd * D);
    const float4* arow = (const float4*)(bases + (size_t)r * 2 * D);      // A0 then A1

    // coalesced 1KB row loads: lane i takes float4 #i of each row
    float4 a0 = arow[lane];
    float4 a1 = arow[D4 + lane];
    float4 re = hrow[lane];
    re.x *= mult; re.y *= mult; re.z *= mult; re.w *= mult;

    float4 eph = e[(size_t)ph * D4 + lane];
    float4 ept = e[(size_t)pt * D4 + lane];
    float4 enh = e[(size_t)nh * D4 + lane];
    float4 ent = e[(size_t)nt * D4 + lane];

    float4 ps, ns;
    ps.x = eph.x + re.x - ept.x;  ns.x = enh.x + re.x - ent.x;
    ps.y = eph.y + re.y - ept.y;  ns.y = enh.y + re.y - ent.y;
    ps.z = eph.z + re.z - ept.z;  ns.z = enh.z + re.z - ent.z;
    ps.w = eph.w + re.w - ept.w;  ns.w = enh.w + re.w - ent.w;

    // 7 wave-wide dot products
    float aa = wsum(dot4(a0, a0));
    float ab = wsum(dot4(a0, a1));
    float dd = wsum(dot4(a1, a1));
    float p0 = wsum(dot4(a0, ps));
    float p1 = wsum(dot4(a1, ps));
    float n0 = wsum(dot4(a0, ns));
    float n1 = wsum(dot4(a1, ns));

    // 2x2 solve: coef = ATA_inv * Asub  (replicated per lane; b==c==ab)
    float det = aa * dd - ab * ab;
    float cp0, cp1, cn0, cn1;
    if (det != 0.0f) {
        float inv = 1.0f / det;
        cp0 = (dd * p0 - ab * p1) * inv;
        cp1 = (aa * p1 - ab * p0) * inv;
        cn0 = (dd * n0 - ab * n1) * inv;
        cn1 = (aa * n1 - ab * n0) * inv;
    } else {
        float inv = 1.0f / aa;   // fallback: ATA_inv = I / a
        cp0 = p0 * inv; cp1 = p1 * inv;
        cn0 = n0 * inv; cn1 = n1 * inv;
    }

    // proj = sub - A^T coef ; score = ||proj||^2
    float4 pp, pn;
    pp.x = ps.x - cp0 * a0.x - cp1 * a1.x;  pn.x = ns.x - cn0 * a0.x - cn1 * a1.x;
    pp.y = ps.y - cp0 * a0.y - cp1 * a1.y;  pn.y = ns.y - cn0 * a0.y - cn1 * a1.y;
    pp.z = ps.z - cp0 * a0.z - cp1 * a1.z;  pn.z = ns.z - cn0 * a0.z - cn1 * a1.z;
    pp.w = ps.w - cp0 * a0.w - cp1 * a1.w;  pn.w = ns.w - cn0 * a0.w - cn1 * a1.w;

    float sp = wsum(dot4(pp, pp));
    float sn = wsum(dot4(pn, pn));

    if (lane == 0) {
        out[b]      = sp;
        out[nB + b] = sn;
    }
}

extern "C" void kernel_launch(void* const* d_in, const int* in_sizes, int n_in,
                              void* d_out, int out_size, void* d_ws, size_t ws_size,
                              hipStream_t stream) {
    const int*   pos_h    = (const int*)  d_in[0];
    const int*   pos_t    = (const int*)  d_in[1];
    const int*   pos_r    = (const int*)  d_in[2];
    const int*   neg_h    = (const int*)  d_in[3];
    const int*   neg_t    = (const int*)  d_in[4];
    // d_in[5] = neg_r (unused by the reference scores)
    const float* ent_emb  = (const float*)d_in[6];
    const float* heads    = (const float*)d_in[7];
    const float* bases    = (const float*)d_in[8];
    const int*   rel2head = (const int*)  d_in[9];
    const float* rel2mult = (const float*)d_in[10];
    float* out = (float*)d_out;

    const int nB = in_sizes[0];               // 65536
    const int waves_per_block = 4;            // 256 threads
    dim3 grid((nB + waves_per_block - 1) / waves_per_block);
    dim3 block(256);
    transint_kernel<<<grid, block, 0, stream>>>(
        pos_h, pos_t, pos_r, neg_h, neg_t,
        ent_emb, heads, bases, rel2head, rel2mult,
        out, nB);
}